// Round 4
// baseline (761.914 us; speedup 1.0000x reference)
//
#include <hip/hip_runtime.h>
#include <stdint.h>
#include <float.h>

#define STRIDE 128
#define NVOX (STRIDE * STRIDE * STRIDE)   // 2^21 voxels
#define BINVOX 512                        // voxels per bin (lin-contiguous)
#define NBIN (NVOX / BINVOX)              // 4096 bins
#define NBITW (NVOX / 32)                 // 65536 bitmap words

typedef unsigned long long u64;

// Order-preserving float32 -> uint32 encoding. enc of any finite float > 0,
// so LDS slots initialized to 0 never win the max for occupied voxels.
__device__ __forceinline__ uint32_t enc_f32(float f) {
  uint32_t u = __float_as_uint(f);
  return (u & 0x80000000u) ? ~u : (u | 0x80000000u);
}
__device__ __forceinline__ float dec_f32(uint32_t e) {
  uint32_t u = (e & 0x80000000u) ? (e & 0x7fffffffu) : ~e;
  return __uint_as_float(u);
}

// pack (cnt low32, occ high32)
__device__ __forceinline__ u64 pack2(uint32_t cnt, uint32_t occ) {
  return (u64)cnt | ((u64)occ << 32);
}

// 1: lin per point + hot-region histogram (bitmap 256KB + bin counts 16KB)
__global__ void k_hist(const float* __restrict__ pos, const float* __restrict__ vs_p,
                       int* __restrict__ lin_arr, uint32_t* __restrict__ bitmap,
                       uint32_t* __restrict__ bin_cnt, int n) {
  int i = blockIdx.x * blockDim.x + threadIdx.x;
  if (i >= n) return;
  float vs = vs_p[0];
  float x = pos[3 * (size_t)i + 0];
  float y = pos[3 * (size_t)i + 1];
  float z = pos[3 * (size_t)i + 2];
  int cx = (int)floorf(x / vs);
  int cy = (int)floorf(y / vs);
  int cz = (int)floorf(z / vs);
  int lin = cx + STRIDE * cy + STRIDE * STRIDE * cz;
  lin_arr[i] = lin;
  atomicOr(&bitmap[lin >> 5], 1u << (lin & 31));
  atomicAdd(&bin_cnt[lin >> 9], 1u);
}

// 2: single-block scan over 4096 bins: point base/cursor + occupied-rank base + M
__global__ __launch_bounds__(1024) void k_scan(
    const uint32_t* __restrict__ bitmap, const uint32_t* __restrict__ bin_cnt,
    uint32_t* __restrict__ bin_base, uint32_t* __restrict__ cursor,
    uint32_t* __restrict__ occ_base, uint32_t* __restrict__ Mp) {
  __shared__ u64 s[1024];
  int t = threadIdx.x;
  uint32_t cnt[4], occ[4];
  u64 sum = 0;
  #pragma unroll
  for (int j = 0; j < 4; ++j) {
    int b = t * 4 + j;
    cnt[j] = bin_cnt[b];
    const uint4* bw = (const uint4*)(bitmap + (size_t)b * 16);
    uint4 w0 = bw[0], w1 = bw[1], w2 = bw[2], w3 = bw[3];
    uint32_t o = __popc(w0.x) + __popc(w0.y) + __popc(w0.z) + __popc(w0.w) +
                 __popc(w1.x) + __popc(w1.y) + __popc(w1.z) + __popc(w1.w) +
                 __popc(w2.x) + __popc(w2.y) + __popc(w2.z) + __popc(w2.w) +
                 __popc(w3.x) + __popc(w3.y) + __popc(w3.z) + __popc(w3.w);
    occ[j] = o;
    sum += pack2(cnt[j], o);
  }
  s[t] = sum;
  __syncthreads();
  for (int off = 1; off < 1024; off <<= 1) {
    u64 add = (t >= off) ? s[t - off] : 0ull;
    __syncthreads();
    s[t] += add;
    __syncthreads();
  }
  u64 run = s[t] - sum;  // exclusive
  #pragma unroll
  for (int j = 0; j < 4; ++j) {
    int b = t * 4 + j;
    bin_base[b] = (uint32_t)run;
    cursor[b]   = (uint32_t)run;
    occ_base[b] = (uint32_t)(run >> 32);
    run += pack2(cnt[j], occ[j]);
  }
  if (t == 1023) Mp[0] = (uint32_t)(s[1023] >> 32);
}

// 3: partition packed (vinbin<<21 | idx) into per-bin regions (hot cursors)
__global__ void k_part(const int* __restrict__ lin_arr, uint32_t* __restrict__ cursor,
                       uint32_t* __restrict__ pairs, int n) {
  int i = blockIdx.x * blockDim.x + threadIdx.x;
  if (i >= n) return;
  int lin = lin_arr[i];
  uint32_t slot = atomicAdd(&cursor[lin >> 9], 1u);
  pairs[slot] = ((uint32_t)(lin & (BINVOX - 1)) << 21) | (uint32_t)i;
}

// 4: one block per bin; LDS holds 512 voxels x 32 features; 8 threads/point
//    gather the point's full 128B row (coalesced, read exactly once) and
//    atomicMax encoded u32s into LDS. Ranks from bitmap -> contiguous output slab.
__global__ __launch_bounds__(1024) void k_pool(
    const float* __restrict__ feat, const float* __restrict__ vs_p,
    const uint32_t* __restrict__ pairs, const uint32_t* __restrict__ bin_base,
    const uint32_t* __restrict__ bin_cnt, const uint32_t* __restrict__ occ_base,
    const uint32_t* __restrict__ bitmap,
    float* __restrict__ out_pos, float* __restrict__ out_feat,
    float* __restrict__ out_valid) {
  __shared__ uint32_t smax[BINVOX * 32];  // 64 KB
  __shared__ uint32_t sbw[16];
  int bin = blockIdx.x;
  int t = threadIdx.x;
  uint32_t cnt = bin_cnt[bin];
  if (cnt == 0) return;  // uniform exit (before any barrier)
  uint32_t start = bin_base[bin];

  #pragma unroll
  for (int k = 0; k < 16; ++k) smax[t + k * 1024] = 0u;
  if (t < 16) sbw[t] = bitmap[(size_t)bin * 16 + t];
  __syncthreads();

  int q = t & 7;
  const float4* f4 = (const float4*)feat;
  for (uint32_t u = (uint32_t)(t >> 3); u < cnt; u += 128) {
    uint32_t p = pairs[start + u];
    uint32_t idx = p & 0x1FFFFFu;
    uint32_t vb = p >> 21;
    float4 v = f4[(size_t)idx * 8 + q];
    uint32_t* d = &smax[vb * 32 + q * 4];
    atomicMax(&d[0], enc_f32(v.x));
    atomicMax(&d[1], enc_f32(v.y));
    atomicMax(&d[2], enc_f32(v.z));
    atomicMax(&d[3], enc_f32(v.w));
  }
  __syncthreads();

  int vb = t >> 1, half = t & 1;
  uint32_t w = sbw[vb >> 5];
  uint32_t bit = (uint32_t)vb & 31u;
  if ((w >> bit) & 1u) {
    uint32_t lr = __popc(w & ((1u << bit) - 1u));
    for (int ww = 0; ww < (vb >> 5); ++ww) lr += __popc(sbw[ww]);
    uint32_t rank = occ_base[bin] + lr;
    float4* orow = (float4*)(out_feat + (size_t)rank * 32 + half * 16);
    #pragma unroll
    for (int j = 0; j < 4; ++j) {
      const uint32_t* sp = &smax[vb * 32 + half * 16 + j * 4];
      float4 o;
      o.x = dec_f32(sp[0]); o.y = dec_f32(sp[1]);
      o.z = dec_f32(sp[2]); o.w = dec_f32(sp[3]);
      orow[j] = o;
    }
    if (half == 0) {
      float vs = vs_p[0];
      int lin = bin * BINVOX + vb;
      int cx = lin & 127, cy = (lin >> 7) & 127, cz = lin >> 14;
      out_pos[(size_t)rank * 3 + 0] = ((float)cx + 0.5f) * vs;
      out_pos[(size_t)rank * 3 + 1] = ((float)cy + 0.5f) * vs;
      out_pos[(size_t)rank * 3 + 2] = ((float)cz + 0.5f) * vs;
      out_valid[rank] = 1.0f;
    }
  }
}

// 5: zero rows >= M (also wipes the out-tail scratch after use)
__global__ void k_tail(const uint32_t* __restrict__ Mp, float* __restrict__ out_pos,
                       float* __restrict__ out_feat, float* __restrict__ out_valid, int n) {
  size_t gid = (size_t)blockIdx.x * blockDim.x + threadIdx.x;  // n*8 exact
  int row = (int)(gid >> 3);
  int q = (int)(gid & 7);
  uint32_t M = Mp[0];
  if ((uint32_t)row < M) return;
  ((float4*)out_feat)[(size_t)row * 8 + q] = make_float4(0.f, 0.f, 0.f, 0.f);
  if (q == 0) {
    out_pos[(size_t)row * 3 + 0] = 0.f;
    out_pos[(size_t)row * 3 + 1] = 0.f;
    out_pos[(size_t)row * 3 + 2] = 0.f;
    out_valid[row] = 0.f;
  }
}

extern "C" void kernel_launch(void* const* d_in, const int* in_sizes, int n_in,
                              void* d_out, int out_size, void* d_ws, size_t ws_size,
                              hipStream_t stream) {
  const float* pos  = (const float*)d_in[0];
  const float* feat = (const float*)d_in[1];
  const float* vs   = (const float*)d_in[2];
  int n = in_sizes[0] / 3;  // 2,000,000

  float*    out_pos   = (float*)d_out;
  uint32_t* out_feat  = (uint32_t*)(out_pos + (size_t)n * 3);
  float*    out_valid = (float*)((float*)out_feat + (size_t)n * 32);

  // Scratch in the TAIL of the feature output region (~17.1 MB):
  // lin(2M) | pairs(2M) | bitmap(64K) | bin_cnt | bin_base | cursor | occ_base.
  // Occupies rows >= 1,866,352; M <= 1,000,000 distinct voxels, so k_pool
  // (writes rows < M) never touches it; k_tail zeroes it after k_pool reads it.
  size_t scratch_u32 = 2 * (size_t)n + NBITW + 4 * (size_t)NBIN;
  uint32_t* scratch  = out_feat + (size_t)n * 32 - scratch_u32;
  int*      lin      = (int*)scratch;
  uint32_t* pairs    = scratch + n;
  uint32_t* bitmap   = pairs + n;
  uint32_t* bin_cnt  = bitmap + NBITW;
  uint32_t* bin_base = bin_cnt + NBIN;
  uint32_t* cursor   = bin_base + NBIN;
  uint32_t* occ_base = cursor + NBIN;

  uint32_t* Mp = (uint32_t*)d_ws;

  // zero bitmap + bin_cnt (contiguous, 272 KB)
  hipMemsetAsync(bitmap, 0, ((size_t)NBITW + NBIN) * sizeof(uint32_t), stream);

  int nb = (n + 255) / 256;
  k_hist<<<nb, 256, 0, stream>>>(pos, vs, lin, bitmap, bin_cnt, n);
  k_scan<<<1, 1024, 0, stream>>>(bitmap, bin_cnt, bin_base, cursor, occ_base, Mp);
  k_part<<<nb, 256, 0, stream>>>(lin, cursor, pairs, n);
  k_pool<<<NBIN, 1024, 0, stream>>>(feat, vs, pairs, bin_base, bin_cnt, occ_base,
                                    bitmap, out_pos, (float*)out_feat, out_valid);
  k_tail<<<(int)(((size_t)n * 8) / 256), 256, 0, stream>>>(
      Mp, out_pos, (float*)out_feat, out_valid, n);
}

// Round 5
// 566.977 us; speedup vs baseline: 1.3438x; 1.3438x over previous
//
#include <hip/hip_runtime.h>
#include <stdint.h>
#include <float.h>

#define STRIDE 128
#define NVOX (STRIDE * STRIDE * STRIDE)   // 2^21 voxels
#define BINVOX 512                        // voxels per bin (lin-contiguous)
#define NBIN (NVOX / BINVOX)              // 4096 bins
#define NBITW (NVOX / 32)                 // 65536 bitmap u32 words
#define REPS 32                           // cursor replicas per bin (anti-contention)

typedef unsigned long long u64;

// Order-preserving float32 -> uint32 encoding. enc(any finite float) > 0,
// so LDS slots initialized to 0 never win the max for occupied voxels.
__device__ __forceinline__ uint32_t enc_f32(float f) {
  uint32_t u = __float_as_uint(f);
  return (u & 0x80000000u) ? ~u : (u | 0x80000000u);
}
__device__ __forceinline__ float dec_f32(uint32_t e) {
  uint32_t u = (e & 0x80000000u) ? (e & 0x7fffffffu) : ~e;
  return __uint_as_float(u);
}

__device__ __forceinline__ u64 pack2(uint32_t cnt, uint32_t occ) {
  return (u64)cnt | ((u64)occ << 32);
}

// 1: lin per point + occupancy bitmap + replicated bin histogram
__global__ void k_hist(const float* __restrict__ pos, const float* __restrict__ vs_p,
                       int* __restrict__ lin_arr, uint32_t* __restrict__ bitmap,
                       uint32_t* __restrict__ cnt, int n) {
  int i = blockIdx.x * blockDim.x + threadIdx.x;
  if (i >= n) return;
  float vs = vs_p[0];
  float x = pos[3 * (size_t)i + 0];
  float y = pos[3 * (size_t)i + 1];
  float z = pos[3 * (size_t)i + 2];
  int cx = (int)floorf(x / vs);
  int cy = (int)floorf(y / vs);
  int cz = (int)floorf(z / vs);
  int lin = cx + STRIDE * cy + STRIDE * STRIDE * cz;
  lin_arr[i] = lin;
  atomicOr(&bitmap[lin >> 5], 1u << (lin & 31));
  atomicAdd(&cnt[(lin >> 9) * REPS + (blockIdx.x & (REPS - 1))], 1u);
}

// 2: single-block scan over 4096 bins: per-(bin,rep) cursors, bin bases,
//    occupied-rank bases, total M.
__global__ __launch_bounds__(1024) void k_scan(
    const uint32_t* __restrict__ bitmap, const uint32_t* __restrict__ cnt,
    uint32_t* __restrict__ cursor, uint32_t* __restrict__ bin_base,
    uint32_t* __restrict__ bin_cnt_tot, uint32_t* __restrict__ occ_base,
    uint32_t* __restrict__ Mp) {
  __shared__ u64 s[1024];
  int t = threadIdx.x;
  uint32_t cbin[4], obin[4];
  u64 sum = 0;
  #pragma unroll
  for (int j = 0; j < 4; ++j) {
    int b = t * 4 + j;
    const uint4* cp = (const uint4*)(cnt + (size_t)b * REPS);
    uint32_t c = 0;
    #pragma unroll
    for (int k = 0; k < 8; ++k) {
      uint4 v = cp[k];
      c += v.x + v.y + v.z + v.w;
    }
    const uint4* bw = (const uint4*)(bitmap + (size_t)b * 16);
    uint4 w0 = bw[0], w1 = bw[1], w2 = bw[2], w3 = bw[3];
    uint32_t o = __popc(w0.x) + __popc(w0.y) + __popc(w0.z) + __popc(w0.w) +
                 __popc(w1.x) + __popc(w1.y) + __popc(w1.z) + __popc(w1.w) +
                 __popc(w2.x) + __popc(w2.y) + __popc(w2.z) + __popc(w2.w) +
                 __popc(w3.x) + __popc(w3.y) + __popc(w3.z) + __popc(w3.w);
    cbin[j] = c;
    obin[j] = o;
    sum += pack2(c, o);
  }
  s[t] = sum;
  __syncthreads();
  for (int off = 1; off < 1024; off <<= 1) {
    u64 add = (t >= off) ? s[t - off] : 0ull;
    __syncthreads();
    s[t] += add;
    __syncthreads();
  }
  u64 run = s[t] - sum;  // exclusive
  #pragma unroll
  for (int j = 0; j < 4; ++j) {
    int b = t * 4 + j;
    uint32_t base = (uint32_t)run;
    bin_base[b]    = base;
    bin_cnt_tot[b] = cbin[j];
    occ_base[b]    = (uint32_t)(run >> 32);
    const uint4* cp = (const uint4*)(cnt + (size_t)b * REPS);
    uint32_t cb = base;
    #pragma unroll
    for (int k = 0; k < 8; ++k) {
      uint4 v = cp[k];
      cursor[(size_t)b * REPS + k * 4 + 0] = cb; cb += v.x;
      cursor[(size_t)b * REPS + k * 4 + 1] = cb; cb += v.y;
      cursor[(size_t)b * REPS + k * 4 + 2] = cb; cb += v.z;
      cursor[(size_t)b * REPS + k * 4 + 3] = cb; cb += v.w;
    }
    run += pack2(cbin[j], obin[j]);
  }
  if (t == 1023) Mp[0] = (uint32_t)(s[1023] >> 32);
}

// 3: partition packed (vinbin<<21 | idx) into per-bin regions (replicated cursors)
__global__ void k_part(const int* __restrict__ lin_arr, uint32_t* __restrict__ cursor,
                       uint32_t* __restrict__ pairs, int n) {
  int i = blockIdx.x * blockDim.x + threadIdx.x;
  if (i >= n) return;
  int lin = lin_arr[i];
  uint32_t slot = atomicAdd(&cursor[(size_t)(lin >> 9) * REPS + (blockIdx.x & (REPS - 1))], 1u);
  pairs[slot] = ((uint32_t)(lin & (BINVOX - 1)) << 21) | (uint32_t)i;
}

// 4: one block per bin; LDS holds 512 voxels x 32 channels (encoded u32).
//    Threads = 32 groups x 32 channels; LDS bank == channel -> conflict-free
//    atomics; 4-wide clamped gather keeps 4 feature loads in flight per lane.
__global__ __launch_bounds__(1024) void k_pool(
    const float* __restrict__ feat, const float* __restrict__ vs_p,
    const uint32_t* __restrict__ pairs, const uint32_t* __restrict__ bin_base,
    const uint32_t* __restrict__ bin_cnt_tot, const uint32_t* __restrict__ occ_base,
    const uint32_t* __restrict__ bitmap,
    float* __restrict__ out_pos, float* __restrict__ out_feat,
    float* __restrict__ out_valid) {
  __shared__ uint32_t smax[BINVOX * 32];  // 64 KB
  __shared__ uint32_t sbw[16];
  int bin = blockIdx.x;
  int t = threadIdx.x;
  uint32_t cnt = bin_cnt_tot[bin];
  if (cnt == 0) return;  // uniform exit (before any barrier)
  uint32_t start = bin_base[bin];

  #pragma unroll
  for (int k = 0; k < 16; ++k) smax[t + k * 1024] = 0u;
  if (t < 16) sbw[t] = bitmap[(size_t)bin * 16 + t];
  __syncthreads();

  int g = t >> 5;    // point group 0..31
  int ch = t & 31;   // channel
  uint32_t last = cnt - 1;
  for (uint32_t u = (uint32_t)g; u < cnt; u += 128) {
    uint32_t u1 = min(u + 32u, last), u2 = min(u + 64u, last), u3 = min(u + 96u, last);
    uint32_t p0 = pairs[start + u],  p1 = pairs[start + u1];
    uint32_t p2 = pairs[start + u2], p3 = pairs[start + u3];
    float v0 = feat[(size_t)(p0 & 0x1FFFFFu) * 32 + ch];
    float v1 = feat[(size_t)(p1 & 0x1FFFFFu) * 32 + ch];
    float v2 = feat[(size_t)(p2 & 0x1FFFFFu) * 32 + ch];
    float v3 = feat[(size_t)(p3 & 0x1FFFFFu) * 32 + ch];
    atomicMax(&smax[(p0 >> 21) * 32 + ch], enc_f32(v0));
    atomicMax(&smax[(p1 >> 21) * 32 + ch], enc_f32(v1));
    atomicMax(&smax[(p2 >> 21) * 32 + ch], enc_f32(v2));
    atomicMax(&smax[(p3 >> 21) * 32 + ch], enc_f32(v3));
  }
  __syncthreads();

  int vb = t >> 1, half = t & 1;
  uint32_t w = sbw[vb >> 5];
  uint32_t bit = (uint32_t)vb & 31u;
  if ((w >> bit) & 1u) {
    uint32_t lr = __popc(w & ((1u << bit) - 1u));
    for (int ww = 0; ww < (vb >> 5); ++ww) lr += __popc(sbw[ww]);
    uint32_t rank = occ_base[bin] + lr;
    float4* orow = (float4*)(out_feat + (size_t)rank * 32 + half * 16);
    #pragma unroll
    for (int j = 0; j < 4; ++j) {
      const uint32_t* sp = &smax[vb * 32 + half * 16 + j * 4];
      float4 o;
      o.x = dec_f32(sp[0]); o.y = dec_f32(sp[1]);
      o.z = dec_f32(sp[2]); o.w = dec_f32(sp[3]);
      orow[j] = o;
    }
    if (half == 0) {
      float vs = vs_p[0];
      int lin = bin * BINVOX + vb;
      int cx = lin & 127, cy = (lin >> 7) & 127, cz = lin >> 14;
      out_pos[(size_t)rank * 3 + 0] = ((float)cx + 0.5f) * vs;
      out_pos[(size_t)rank * 3 + 1] = ((float)cy + 0.5f) * vs;
      out_pos[(size_t)rank * 3 + 2] = ((float)cz + 0.5f) * vs;
      out_valid[rank] = 1.0f;
    }
  }
}

// 5: zero rows >= M (also wipes the out-tail scratch after use)
__global__ void k_tail(const uint32_t* __restrict__ Mp, float* __restrict__ out_pos,
                       float* __restrict__ out_feat, float* __restrict__ out_valid, int n) {
  size_t gid = (size_t)blockIdx.x * blockDim.x + threadIdx.x;  // n*8 exact
  int row = (int)(gid >> 3);
  int q = (int)(gid & 7);
  uint32_t M = Mp[0];
  if ((uint32_t)row < M) return;
  ((float4*)out_feat)[(size_t)row * 8 + q] = make_float4(0.f, 0.f, 0.f, 0.f);
  if (q == 0) {
    out_pos[(size_t)row * 3 + 0] = 0.f;
    out_pos[(size_t)row * 3 + 1] = 0.f;
    out_pos[(size_t)row * 3 + 2] = 0.f;
    out_valid[row] = 0.f;
  }
}

extern "C" void kernel_launch(void* const* d_in, const int* in_sizes, int n_in,
                              void* d_out, int out_size, void* d_ws, size_t ws_size,
                              hipStream_t stream) {
  const float* pos  = (const float*)d_in[0];
  const float* feat = (const float*)d_in[1];
  const float* vs   = (const float*)d_in[2];
  int n = in_sizes[0] / 3;  // 2,000,000

  float*    out_pos   = (float*)d_out;
  uint32_t* out_feat  = (uint32_t*)(out_pos + (size_t)n * 3);
  float*    out_valid = (float*)((float*)out_feat + (size_t)n * 32);

  // Scratch in the TAIL of the feature output region (~17.4 MB):
  // lin(n) | pairs(n) | bitmap | cnt[NBIN*REPS] | cursor[NBIN*REPS] |
  // bin_base | bin_cnt_tot | occ_base.  Rows >= ~1,864,376; M < 1e6, so
  // k_pool (writes rows < M) never touches it; k_tail zeroes it after use.
  size_t scratch_u32 = 2 * (size_t)n + NBITW + 2 * (size_t)NBIN * REPS + 3 * (size_t)NBIN;
  uint32_t* scratch     = out_feat + (size_t)n * 32 - scratch_u32;
  int*      lin         = (int*)scratch;
  uint32_t* pairs       = scratch + n;
  uint32_t* bitmap      = pairs + n;
  uint32_t* cnt         = bitmap + NBITW;          // NBIN*REPS
  uint32_t* cursor      = cnt + (size_t)NBIN * REPS;
  uint32_t* bin_base    = cursor + (size_t)NBIN * REPS;
  uint32_t* bin_cnt_tot = bin_base + NBIN;
  uint32_t* occ_base    = bin_cnt_tot + NBIN;

  uint32_t* Mp = (uint32_t*)d_ws;

  // zero bitmap + cnt (contiguous, 768 KB)
  hipMemsetAsync(bitmap, 0, ((size_t)NBITW + (size_t)NBIN * REPS) * sizeof(uint32_t), stream);

  int nb = (n + 255) / 256;
  k_hist<<<nb, 256, 0, stream>>>(pos, vs, lin, bitmap, cnt, n);
  k_scan<<<1, 1024, 0, stream>>>(bitmap, cnt, cursor, bin_base, bin_cnt_tot, occ_base, Mp);
  k_part<<<nb, 256, 0, stream>>>(lin, cursor, pairs, n);
  k_pool<<<NBIN, 1024, 0, stream>>>(feat, vs, pairs, bin_base, bin_cnt_tot, occ_base,
                                    bitmap, out_pos, (float*)out_feat, out_valid);
  k_tail<<<(int)(((size_t)n * 8) / 256), 256, 0, stream>>>(
      Mp, out_pos, (float*)out_feat, out_valid, n);
}

// Round 6
// 230.709 us; speedup vs baseline: 3.3025x; 2.4575x over previous
//
#include <hip/hip_runtime.h>
#include <stdint.h>

#define STRIDE 128
#define NVOX (STRIDE * STRIDE * STRIDE)   // 2^21 voxels
#define BINVOX 512                        // voxels per bin (lin-contiguous)
#define NBIN (NVOX / BINVOX)              // 4096 bins
#define HB 256                            // partition blocks (chunks)
#define HT 1024                           // threads per partition block

typedef unsigned long long u64;

// Order-preserving float32 -> uint32 encoding. enc(any finite float) > 0,
// so LDS slots initialized to 0 never win the max for occupied voxels.
__device__ __forceinline__ uint32_t enc_f32(float f) {
  uint32_t u = __float_as_uint(f);
  return (u & 0x80000000u) ? ~u : (u | 0x80000000u);
}
__device__ __forceinline__ float dec_f32(uint32_t e) {
  uint32_t u = (e & 0x80000000u) ? (e & 0x7fffffffu) : ~e;
  return __uint_as_float(u);
}

// 1: per-chunk private LDS histogram (no global atomics) + lin cache
__global__ __launch_bounds__(HT) void k_hist(const float* __restrict__ pos,
                                             const float* __restrict__ vs_p,
                                             int* __restrict__ lin_arr,
                                             uint32_t* __restrict__ hist, int n) {
  __shared__ uint32_t h[NBIN];  // 16 KB
  int b = blockIdx.x, t = threadIdx.x;
  #pragma unroll
  for (int k = t; k < NBIN; k += HT) h[k] = 0u;
  __syncthreads();
  int chunk = (n + HB - 1) / HB;
  int i0 = b * chunk, i1 = min(n, i0 + chunk);
  float vs = vs_p[0];
  for (int i = i0 + t; i < i1; i += HT) {
    float x = pos[3 * (size_t)i + 0];
    float y = pos[3 * (size_t)i + 1];
    float z = pos[3 * (size_t)i + 2];
    int lin = (int)floorf(x / vs) + STRIDE * (int)floorf(y / vs) +
              STRIDE * STRIDE * (int)floorf(z / vs);
    lin_arr[i] = lin;
    atomicAdd(&h[lin >> 9], 1u);  // LDS atomic
  }
  __syncthreads();
  #pragma unroll
  for (int k = t; k < NBIN; k += HT) hist[(size_t)b * NBIN + k] = h[k];
}

// 2: per-bin exclusive scan across the 256 chunk histograms
__global__ void k_scanA(const uint32_t* __restrict__ hist, uint32_t* __restrict__ base2,
                        uint32_t* __restrict__ bin_tot) {
  int bin = blockIdx.x * blockDim.x + threadIdx.x;  // 4096 threads total
  uint32_t run = 0;
  #pragma unroll 8
  for (int b = 0; b < HB; ++b) {
    uint32_t v = hist[(size_t)b * NBIN + bin];
    base2[(size_t)b * NBIN + bin] = run;
    run += v;
  }
  bin_tot[bin] = run;
}

// 3: single-block exclusive scan over 4096 u32 (optionally emits total)
__global__ __launch_bounds__(1024) void k_scan4k(const uint32_t* __restrict__ in,
                                                 uint32_t* __restrict__ out,
                                                 uint32_t* __restrict__ Mp) {
  __shared__ uint32_t s[1024];
  int t = threadIdx.x;
  uint32_t v[4], sum = 0;
  #pragma unroll
  for (int j = 0; j < 4; ++j) { v[j] = in[t * 4 + j]; sum += v[j]; }
  s[t] = sum;
  __syncthreads();
  for (int off = 1; off < 1024; off <<= 1) {
    uint32_t a = (t >= off) ? s[t - off] : 0u;
    __syncthreads();
    s[t] += a;
    __syncthreads();
  }
  uint32_t run = s[t] - sum;
  #pragma unroll
  for (int j = 0; j < 4; ++j) { out[t * 4 + j] = run; run += v[j]; }
  if (Mp != nullptr && t == 1023) Mp[0] = s[1023];
}

// 4: partition with LDS cursors (no global atomics); same chunk map as k_hist
__global__ __launch_bounds__(HT) void k_part(const int* __restrict__ lin_arr,
                                             const uint32_t* __restrict__ bin_base,
                                             const uint32_t* __restrict__ base2,
                                             uint32_t* __restrict__ pairs, int n) {
  __shared__ uint32_t cur[NBIN];  // 16 KB
  int b = blockIdx.x, t = threadIdx.x;
  #pragma unroll
  for (int k = t; k < NBIN; k += HT)
    cur[k] = bin_base[k] + base2[(size_t)b * NBIN + k];
  __syncthreads();
  int chunk = (n + HB - 1) / HB;
  int i0 = b * chunk, i1 = min(n, i0 + chunk);
  for (int i = i0 + t; i < i1; i += HT) {
    int lin = lin_arr[i];
    uint32_t slot = atomicAdd(&cur[lin >> 9], 1u);  // LDS atomic
    pairs[slot] = ((uint32_t)(lin & (BINVOX - 1)) << 21) | (uint32_t)i;
  }
}

// 5: per-bin 512-bit occupancy bitmap from pairs (LDS atomicOr) + occupied count
__global__ void k_occ(const uint32_t* __restrict__ pairs,
                      const uint32_t* __restrict__ bin_base,
                      const uint32_t* __restrict__ bin_tot,
                      uint32_t* __restrict__ bins_bw, uint32_t* __restrict__ occ_cnt) {
  __shared__ uint32_t bw[16];
  int bin = blockIdx.x, t = threadIdx.x;
  if (t < 16) bw[t] = 0u;
  __syncthreads();
  uint32_t cnt = bin_tot[bin], start = bin_base[bin];
  for (uint32_t u = (uint32_t)t; u < cnt; u += blockDim.x) {
    uint32_t vb = pairs[start + u] >> 21;
    atomicOr(&bw[vb >> 5], 1u << (vb & 31));
  }
  __syncthreads();
  if (t < 16) bins_bw[(size_t)bin * 16 + t] = bw[t];
  if (t == 0) {
    uint32_t o = 0;
    #pragma unroll
    for (int w = 0; w < 16; ++w) o += __popc(bw[w]);
    occ_cnt[bin] = o;
  }
}

// 6: one block per bin; LDS 512 voxels x 32 channels; channel==bank ->
//    conflict-light LDS atomics; 4-wide clamped gather for MLP.
__global__ __launch_bounds__(1024) void k_pool(
    const float* __restrict__ feat, const float* __restrict__ vs_p,
    const uint32_t* __restrict__ pairs, const uint32_t* __restrict__ bin_base,
    const uint32_t* __restrict__ bin_tot, const uint32_t* __restrict__ occ_base,
    const uint32_t* __restrict__ bins_bw,
    float* __restrict__ out_pos, float* __restrict__ out_feat,
    float* __restrict__ out_valid) {
  __shared__ uint32_t smax[BINVOX * 32];  // 64 KB
  __shared__ uint32_t sbw[16];
  int bin = blockIdx.x;
  int t = threadIdx.x;
  uint32_t cnt = bin_tot[bin];
  if (cnt == 0) return;  // uniform exit (before any barrier)
  uint32_t start = bin_base[bin];

  #pragma unroll
  for (int k = 0; k < 16; ++k) smax[t + k * 1024] = 0u;
  if (t < 16) sbw[t] = bins_bw[(size_t)bin * 16 + t];
  __syncthreads();

  int g = t >> 5;    // point group 0..31
  int ch = t & 31;   // channel
  uint32_t last = cnt - 1;
  for (uint32_t u = (uint32_t)g; u < cnt; u += 128) {
    uint32_t u1 = min(u + 32u, last), u2 = min(u + 64u, last), u3 = min(u + 96u, last);
    uint32_t p0 = pairs[start + u],  p1 = pairs[start + u1];
    uint32_t p2 = pairs[start + u2], p3 = pairs[start + u3];
    float v0 = feat[(size_t)(p0 & 0x1FFFFFu) * 32 + ch];
    float v1 = feat[(size_t)(p1 & 0x1FFFFFu) * 32 + ch];
    float v2 = feat[(size_t)(p2 & 0x1FFFFFu) * 32 + ch];
    float v3 = feat[(size_t)(p3 & 0x1FFFFFu) * 32 + ch];
    atomicMax(&smax[(p0 >> 21) * 32 + ch], enc_f32(v0));
    atomicMax(&smax[(p1 >> 21) * 32 + ch], enc_f32(v1));
    atomicMax(&smax[(p2 >> 21) * 32 + ch], enc_f32(v2));
    atomicMax(&smax[(p3 >> 21) * 32 + ch], enc_f32(v3));
  }
  __syncthreads();

  int vb = t >> 1, half = t & 1;
  uint32_t w = sbw[vb >> 5];
  uint32_t bit = (uint32_t)vb & 31u;
  if ((w >> bit) & 1u) {
    uint32_t lr = __popc(w & ((1u << bit) - 1u));
    for (int ww = 0; ww < (vb >> 5); ++ww) lr += __popc(sbw[ww]);
    uint32_t rank = occ_base[bin] + lr;
    float4* orow = (float4*)(out_feat + (size_t)rank * 32 + half * 16);
    #pragma unroll
    for (int j = 0; j < 4; ++j) {
      const uint32_t* sp = &smax[vb * 32 + half * 16 + j * 4];
      float4 o;
      o.x = dec_f32(sp[0]); o.y = dec_f32(sp[1]);
      o.z = dec_f32(sp[2]); o.w = dec_f32(sp[3]);
      orow[j] = o;
    }
    if (half == 0) {
      float vs = vs_p[0];
      int lin = bin * BINVOX + vb;
      int cx = lin & 127, cy = (lin >> 7) & 127, cz = lin >> 14;
      out_pos[(size_t)rank * 3 + 0] = ((float)cx + 0.5f) * vs;
      out_pos[(size_t)rank * 3 + 1] = ((float)cy + 0.5f) * vs;
      out_pos[(size_t)rank * 3 + 2] = ((float)cz + 0.5f) * vs;
      out_valid[rank] = 1.0f;
    }
  }
}

// 7: zero rows >= M (also wipes the out-tail scratch after use)
__global__ void k_tail(const uint32_t* __restrict__ Mp, float* __restrict__ out_pos,
                       float* __restrict__ out_feat, float* __restrict__ out_valid, int n) {
  size_t gid = (size_t)blockIdx.x * blockDim.x + threadIdx.x;
  int row = (int)(gid >> 3);
  int q = (int)(gid & 7);
  if (row >= n) return;
  uint32_t M = Mp[0];
  if ((uint32_t)row < M) return;
  ((float4*)out_feat)[(size_t)row * 8 + q] = make_float4(0.f, 0.f, 0.f, 0.f);
  if (q == 0) {
    out_pos[(size_t)row * 3 + 0] = 0.f;
    out_pos[(size_t)row * 3 + 1] = 0.f;
    out_pos[(size_t)row * 3 + 2] = 0.f;
    out_valid[row] = 0.f;
  }
}

extern "C" void kernel_launch(void* const* d_in, const int* in_sizes, int n_in,
                              void* d_out, int out_size, void* d_ws, size_t ws_size,
                              hipStream_t stream) {
  const float* pos  = (const float*)d_in[0];
  const float* feat = (const float*)d_in[1];
  const float* vs   = (const float*)d_in[2];
  int n = in_sizes[0] / 3;  // 2,000,000

  float*    out_pos   = (float*)d_out;
  uint32_t* out_feat  = (uint32_t*)(out_pos + (size_t)n * 3);
  float*    out_valid = (float*)((float*)out_feat + (size_t)n * 32);

  // Scratch in the TAIL of the feature output region (~24.7 MB):
  // lin(n) | pairs(n) | hist[HB][NBIN] | base2[HB][NBIN] | bin_tot | bin_base |
  // occ_cnt | occ_base | bins_bw[NBIN][16].
  // Occupies rows >= ~1,806,904; positions in [0,100)^3 -> at most 100^3 = 1e6
  // distinct voxels, so M <= 1,000,000 and k_pool (writes rows < M) never
  // touches the scratch; k_tail zeroes it after use. Every scratch word is
  // fully rewritten each call (no memset needed; deterministic across replays).
  size_t scratch_u32 = 2 * (size_t)n + 2 * (size_t)HB * NBIN + 4 * (size_t)NBIN +
                       16 * (size_t)NBIN;
  uint32_t* scratch  = out_feat + (size_t)n * 32 - scratch_u32;
  int*      lin      = (int*)scratch;
  uint32_t* pairs    = scratch + n;
  uint32_t* hist     = pairs + n;                       // HB*NBIN
  uint32_t* base2    = hist + (size_t)HB * NBIN;        // HB*NBIN
  uint32_t* bin_tot  = base2 + (size_t)HB * NBIN;       // NBIN
  uint32_t* bin_base = bin_tot + NBIN;                  // NBIN
  uint32_t* occ_cnt  = bin_base + NBIN;                 // NBIN
  uint32_t* occ_base = occ_cnt + NBIN;                  // NBIN
  uint32_t* bins_bw  = occ_base + NBIN;                 // NBIN*16

  uint32_t* Mp = (uint32_t*)d_ws;

  k_hist<<<HB, HT, 0, stream>>>(pos, vs, lin, hist, n);
  k_scanA<<<NBIN / 256, 256, 0, stream>>>(hist, base2, bin_tot);
  k_scan4k<<<1, 1024, 0, stream>>>(bin_tot, bin_base, nullptr);
  k_part<<<HB, HT, 0, stream>>>(lin, bin_base, base2, pairs, n);
  k_occ<<<NBIN, 256, 0, stream>>>(pairs, bin_base, bin_tot, bins_bw, occ_cnt);
  k_scan4k<<<1, 1024, 0, stream>>>(occ_cnt, occ_base, Mp);
  k_pool<<<NBIN, 1024, 0, stream>>>(feat, vs, pairs, bin_base, bin_tot, occ_base,
                                    bins_bw, out_pos, (float*)out_feat, out_valid);
  k_tail<<<(int)(((size_t)n * 8 + 255) / 256), 256, 0, stream>>>(
      Mp, out_pos, (float*)out_feat, out_valid, n);
}

// Round 7
// 224.952 us; speedup vs baseline: 3.3870x; 1.0256x over previous
//
#include <hip/hip_runtime.h>
#include <stdint.h>

#define STRIDE 128
#define NVOX (STRIDE * STRIDE * STRIDE)   // 2^21 voxels
#define BINVOX 512                        // voxels per bin (lin-contiguous)
#define NBIN (NVOX / BINVOX)              // 4096 bins
#define HB 256                            // partition blocks (chunks)
#define HT 1024                           // threads per partition block

typedef unsigned long long u64;

// Order-preserving float32 -> uint32 encoding. enc(any finite float) > 0,
// so LDS slots initialized to 0 never win the max for occupied voxels.
__device__ __forceinline__ uint32_t enc_f32(float f) {
  uint32_t u = __float_as_uint(f);
  return (u & 0x80000000u) ? ~u : (u | 0x80000000u);
}
__device__ __forceinline__ float dec_f32(uint32_t e) {
  uint32_t u = (e & 0x80000000u) ? (e & 0x7fffffffu) : ~e;
  return __uint_as_float(u);
}

// 1: per-chunk private LDS histogram + lin cache + occupancy bytemap (plain
//    idempotent byte stores -- no global atomics anywhere).
__global__ __launch_bounds__(HT) void k_hist(const float* __restrict__ pos,
                                             const float* __restrict__ vs_p,
                                             int* __restrict__ lin_arr,
                                             uint8_t* __restrict__ bytemap,
                                             uint32_t* __restrict__ hist, int n) {
  __shared__ uint32_t h[NBIN];  // 16 KB
  int b = blockIdx.x, t = threadIdx.x;
  #pragma unroll
  for (int k = t; k < NBIN; k += HT) h[k] = 0u;
  __syncthreads();
  int chunk = (n + HB - 1) / HB;
  int i0 = b * chunk, i1 = min(n, i0 + chunk);
  float vs = vs_p[0];
  for (int i = i0 + t; i < i1; i += HT) {
    float x = pos[3 * (size_t)i + 0];
    float y = pos[3 * (size_t)i + 1];
    float z = pos[3 * (size_t)i + 2];
    int lin = (int)floorf(x / vs) + STRIDE * (int)floorf(y / vs) +
              STRIDE * STRIDE * (int)floorf(z / vs);
    lin_arr[i] = lin;
    bytemap[lin] = 1;
    atomicAdd(&h[lin >> 9], 1u);  // LDS atomic
  }
  __syncthreads();
  #pragma unroll
  for (int k = t; k < NBIN; k += HT) hist[(size_t)b * NBIN + k] = h[k];
}

// 2: per-bin exclusive scan across chunk histograms + occupancy count from
//    bytemap (bytes are 0/1 -> popc per u32 counts them). Emits packed u64.
__global__ void k_scanA(const uint32_t* __restrict__ hist,
                        const uint32_t* __restrict__ bytemap_w,
                        uint32_t* __restrict__ base2, u64* __restrict__ tot2) {
  int bin = blockIdx.x * blockDim.x + threadIdx.x;  // 4096 threads total
  uint32_t run = 0;
  #pragma unroll 8
  for (int b = 0; b < HB; ++b) {
    base2[(size_t)b * NBIN + bin] = run;
    run += hist[(size_t)b * NBIN + bin];
  }
  const uint4* bp = (const uint4*)(bytemap_w) + (size_t)bin * 32;  // 512 B
  uint32_t occ = 0;
  #pragma unroll
  for (int k = 0; k < 32; ++k) {
    uint4 v = bp[k];
    occ += __popc(v.x) + __popc(v.y) + __popc(v.z) + __popc(v.w);
  }
  tot2[bin] = (u64)run | ((u64)occ << 32);
}

// 3: single-block exclusive scan over 4096 packed u64 -> point bases,
//    occupied-rank bases, total M.
__global__ __launch_bounds__(1024) void k_scan64(const u64* __restrict__ in,
                                                 uint32_t* __restrict__ bin_base,
                                                 uint32_t* __restrict__ occ_base,
                                                 uint32_t* __restrict__ Mp) {
  __shared__ u64 s[1024];
  int t = threadIdx.x;
  u64 v[4], sum = 0;
  #pragma unroll
  for (int j = 0; j < 4; ++j) { v[j] = in[t * 4 + j]; sum += v[j]; }
  s[t] = sum;
  __syncthreads();
  for (int off = 1; off < 1024; off <<= 1) {
    u64 a = (t >= off) ? s[t - off] : 0ull;
    __syncthreads();
    s[t] += a;
    __syncthreads();
  }
  u64 run = s[t] - sum;
  #pragma unroll
  for (int j = 0; j < 4; ++j) {
    bin_base[t * 4 + j] = (uint32_t)run;
    occ_base[t * 4 + j] = (uint32_t)(run >> 32);
    run += v[j];
  }
  if (t == 1023) Mp[0] = (uint32_t)(s[1023] >> 32);
}

// 4: partition with LDS cursors (no global atomics); same chunk map as k_hist
__global__ __launch_bounds__(HT) void k_part(const int* __restrict__ lin_arr,
                                             const uint32_t* __restrict__ bin_base,
                                             const uint32_t* __restrict__ base2,
                                             uint32_t* __restrict__ pairs, int n) {
  __shared__ uint32_t cur[NBIN];  // 16 KB
  int b = blockIdx.x, t = threadIdx.x;
  #pragma unroll
  for (int k = t; k < NBIN; k += HT)
    cur[k] = bin_base[k] + base2[(size_t)b * NBIN + k];
  __syncthreads();
  int chunk = (n + HB - 1) / HB;
  int i0 = b * chunk, i1 = min(n, i0 + chunk);
  for (int i = i0 + t; i < i1; i += HT) {
    int lin = lin_arr[i];
    uint32_t slot = atomicAdd(&cur[lin >> 9], 1u);  // LDS atomic
    pairs[slot] = ((uint32_t)(lin & (BINVOX - 1)) << 21) | (uint32_t)i;
  }
}

// 5: one block per bin; LDS 512 voxels x 32 channels; channel==bank ->
//    conflict-light LDS atomics; 8-wide clamped gather keeps 8 feature
//    loads in flight per lane. Bin occupancy mask rebuilt via ballot.
__global__ __launch_bounds__(1024) void k_pool(
    const float* __restrict__ feat, const float* __restrict__ vs_p,
    const uint32_t* __restrict__ pairs, const uint32_t* __restrict__ bin_base,
    const u64* __restrict__ tot2, const uint32_t* __restrict__ occ_base,
    const uint8_t* __restrict__ bytemap,
    float* __restrict__ out_pos, float* __restrict__ out_feat,
    float* __restrict__ out_valid) {
  __shared__ uint32_t smax[BINVOX * 32];  // 64 KB
  __shared__ u64 sbw[8];
  int bin = blockIdx.x;
  int t = threadIdx.x;
  uint32_t cnt = (uint32_t)tot2[bin];
  if (cnt == 0) return;  // uniform exit (before any barrier)
  uint32_t start = bin_base[bin];

  #pragma unroll
  for (int k = 0; k < 16; ++k) smax[t + k * 1024] = 0u;
  if (t < 512) {  // waves 0..7 exactly; ballot is wave-uniform
    uint32_t occb = bytemap[(size_t)bin * BINVOX + t];
    u64 m = __ballot(occb != 0);
    if ((t & 63) == 0) sbw[t >> 6] = m;
  }
  __syncthreads();

  int g = t >> 5;    // point group 0..31
  int ch = t & 31;   // channel
  uint32_t last = cnt - 1;
  for (uint32_t u = (uint32_t)g; u < cnt; u += 256) {
    uint32_t p0 = pairs[start + u];
    uint32_t p1 = pairs[start + min(u + 32u, last)];
    uint32_t p2 = pairs[start + min(u + 64u, last)];
    uint32_t p3 = pairs[start + min(u + 96u, last)];
    uint32_t p4 = pairs[start + min(u + 128u, last)];
    uint32_t p5 = pairs[start + min(u + 160u, last)];
    uint32_t p6 = pairs[start + min(u + 192u, last)];
    uint32_t p7 = pairs[start + min(u + 224u, last)];
    float v0 = feat[(size_t)(p0 & 0x1FFFFFu) * 32 + ch];
    float v1 = feat[(size_t)(p1 & 0x1FFFFFu) * 32 + ch];
    float v2 = feat[(size_t)(p2 & 0x1FFFFFu) * 32 + ch];
    float v3 = feat[(size_t)(p3 & 0x1FFFFFu) * 32 + ch];
    float v4 = feat[(size_t)(p4 & 0x1FFFFFu) * 32 + ch];
    float v5 = feat[(size_t)(p5 & 0x1FFFFFu) * 32 + ch];
    float v6 = feat[(size_t)(p6 & 0x1FFFFFu) * 32 + ch];
    float v7 = feat[(size_t)(p7 & 0x1FFFFFu) * 32 + ch];
    atomicMax(&smax[(p0 >> 21) * 32 + ch], enc_f32(v0));
    atomicMax(&smax[(p1 >> 21) * 32 + ch], enc_f32(v1));
    atomicMax(&smax[(p2 >> 21) * 32 + ch], enc_f32(v2));
    atomicMax(&smax[(p3 >> 21) * 32 + ch], enc_f32(v3));
    atomicMax(&smax[(p4 >> 21) * 32 + ch], enc_f32(v4));
    atomicMax(&smax[(p5 >> 21) * 32 + ch], enc_f32(v5));
    atomicMax(&smax[(p6 >> 21) * 32 + ch], enc_f32(v6));
    atomicMax(&smax[(p7 >> 21) * 32 + ch], enc_f32(v7));
  }
  __syncthreads();

  int vb = t >> 1, half = t & 1;
  u64 w = sbw[vb >> 6];
  int bit = vb & 63;
  if ((w >> bit) & 1ull) {
    uint32_t lr = (uint32_t)__popcll(w & ((1ull << bit) - 1ull));
    for (int ww = 0; ww < (vb >> 6); ++ww) lr += (uint32_t)__popcll(sbw[ww]);
    uint32_t rank = occ_base[bin] + lr;
    float4* orow = (float4*)(out_feat + (size_t)rank * 32 + half * 16);
    #pragma unroll
    for (int j = 0; j < 4; ++j) {
      const uint32_t* sp = &smax[vb * 32 + half * 16 + j * 4];
      float4 o;
      o.x = dec_f32(sp[0]); o.y = dec_f32(sp[1]);
      o.z = dec_f32(sp[2]); o.w = dec_f32(sp[3]);
      orow[j] = o;
    }
    if (half == 0) {
      float vs = vs_p[0];
      int lin = bin * BINVOX + vb;
      int cx = lin & 127, cy = (lin >> 7) & 127, cz = lin >> 14;
      out_pos[(size_t)rank * 3 + 0] = ((float)cx + 0.5f) * vs;
      out_pos[(size_t)rank * 3 + 1] = ((float)cy + 0.5f) * vs;
      out_pos[(size_t)rank * 3 + 2] = ((float)cz + 0.5f) * vs;
      out_valid[rank] = 1.0f;
    }
  }
}

// 6: zero rows >= M (also wipes the out-tail scratch after use)
__global__ void k_tail(const uint32_t* __restrict__ Mp, float* __restrict__ out_pos,
                       float* __restrict__ out_feat, float* __restrict__ out_valid, int n) {
  size_t gid = (size_t)blockIdx.x * blockDim.x + threadIdx.x;
  int row = (int)(gid >> 3);
  int q = (int)(gid & 7);
  if (row >= n) return;
  uint32_t M = Mp[0];
  if ((uint32_t)row < M) return;
  ((float4*)out_feat)[(size_t)row * 8 + q] = make_float4(0.f, 0.f, 0.f, 0.f);
  if (q == 0) {
    out_pos[(size_t)row * 3 + 0] = 0.f;
    out_pos[(size_t)row * 3 + 1] = 0.f;
    out_pos[(size_t)row * 3 + 2] = 0.f;
    out_valid[row] = 0.f;
  }
}

extern "C" void kernel_launch(void* const* d_in, const int* in_sizes, int n_in,
                              void* d_out, int out_size, void* d_ws, size_t ws_size,
                              hipStream_t stream) {
  const float* pos  = (const float*)d_in[0];
  const float* feat = (const float*)d_in[1];
  const float* vs   = (const float*)d_in[2];
  int n = in_sizes[0] / 3;  // 2,000,000

  float*    out_pos   = (float*)d_out;
  uint32_t* out_feat  = (uint32_t*)(out_pos + (size_t)n * 3);
  float*    out_valid = (float*)((float*)out_feat + (size_t)n * 32);

  // Scratch in the TAIL of the feature output region (~26.6 MB):
  // lin(n) | pairs(n) | hist[HB][NBIN] | base2[HB][NBIN] | tot2(u64 NBIN) |
  // bin_base | occ_base | bytemap(NVOX bytes).
  // Occupies rows >= ~1,792,568; positions in [0,100)^3 -> at most 1e6
  // distinct voxels, so M <= 1,000,000 and k_pool (writes rows < M) never
  // touches the scratch; k_tail zeroes it after use. Every scratch word
  // except bytemap is fully rewritten each call; bytemap is memset below.
  size_t scratch_u32 = 2 * (size_t)n + 2 * (size_t)HB * NBIN + 2 * (size_t)NBIN +
                       2 * (size_t)NBIN + NVOX / 4;
  uint32_t* scratch  = out_feat + (size_t)n * 32 - scratch_u32;
  int*      lin      = (int*)scratch;
  uint32_t* pairs    = scratch + n;
  uint32_t* hist     = pairs + n;                       // HB*NBIN
  uint32_t* base2    = hist + (size_t)HB * NBIN;        // HB*NBIN
  u64*      tot2     = (u64*)(base2 + (size_t)HB * NBIN);  // NBIN u64
  uint32_t* bin_base = (uint32_t*)(tot2 + NBIN);        // NBIN
  uint32_t* occ_base = bin_base + NBIN;                 // NBIN
  uint8_t*  bytemap  = (uint8_t*)(occ_base + NBIN);     // NVOX bytes

  uint32_t* Mp = (uint32_t*)d_ws;

  hipMemsetAsync(bytemap, 0, (size_t)NVOX, stream);  // 2 MB

  k_hist<<<HB, HT, 0, stream>>>(pos, vs, lin, bytemap, hist, n);
  k_scanA<<<NBIN / 256, 256, 0, stream>>>(hist, (const uint32_t*)bytemap, base2, tot2);
  k_scan64<<<1, 1024, 0, stream>>>(tot2, bin_base, occ_base, Mp);
  k_part<<<HB, HT, 0, stream>>>(lin, bin_base, base2, pairs, n);
  k_pool<<<NBIN, 1024, 0, stream>>>(feat, vs, pairs, bin_base, tot2, occ_base,
                                    bytemap, out_pos, (float*)out_feat, out_valid);
  k_tail<<<(int)(((size_t)n * 8 + 255) / 256), 256, 0, stream>>>(
      Mp, out_pos, (float*)out_feat, out_valid, n);
}

// Round 9
// 222.728 us; speedup vs baseline: 3.4208x; 1.0100x over previous
//
#include <hip/hip_runtime.h>
#include <stdint.h>

#define STRIDE 128
#define NVOX (STRIDE * STRIDE * STRIDE)   // 2^21 voxels
#define BINVOX 512                        // voxels per bin (lin-contiguous)
#define NBIN (NVOX / BINVOX)              // 4096 bins
#define HB 256                            // partition blocks (chunks)
#define HT 1024                           // threads per partition block
#define NSEG 16                           // scan blocks
#define SEGBINS (NBIN / NSEG)             // 256 bins per scan block

typedef unsigned long long u64;

// Order-preserving float32 -> uint32 encoding. enc(any finite float) > 0,
// so LDS slots initialized to 0 never win the max for occupied voxels.
__device__ __forceinline__ uint32_t enc_f32(float f) {
  uint32_t u = __float_as_uint(f);
  return (u & 0x80000000u) ? ~u : (u | 0x80000000u);
}
__device__ __forceinline__ float dec_f32(uint32_t e) {
  uint32_t u = (e & 0x80000000u) ? (e & 0x7fffffffu) : ~e;
  return __uint_as_float(u);
}

// EXACT count of bytes equal to 1 in a u32 (poison 0xAA and 0x00 excluded).
// Carry-free zero-byte mask: per-byte (y&0x7F)+0x7F <= 0xFE, no cross-lane
// borrow (the (y-k) SWAR variant miscounts when byte i==0 borrows into i+1).
__device__ __forceinline__ uint32_t cnt_eq1(uint32_t w) {
  uint32_t y = w ^ 0x01010101u;
  uint32_t z = ~(((y & 0x7F7F7F7Fu) + 0x7F7F7F7Fu) | y | 0x7F7F7F7Fu);
  return __popc(z);  // one 0x80 bit per byte of y that is zero (w byte == 1)
}

// 1: per-chunk private LDS histogram + lin cache + occupancy bytemap
//    (plain idempotent byte stores; bytemap needs no pre-zeroing because
//    consumers test bytes == 1 exactly). Also resets the scan sync counter.
__global__ __launch_bounds__(HT) void k_hist(const float* __restrict__ pos,
                                             const float* __restrict__ vs_p,
                                             int* __restrict__ lin_arr,
                                             uint8_t* __restrict__ bytemap,
                                             uint32_t* __restrict__ hist,
                                             uint32_t* __restrict__ sync, int n) {
  __shared__ uint32_t h[NBIN];  // 16 KB
  int b = blockIdx.x, t = threadIdx.x;
  if (b == 0 && t == 0) *sync = 0u;  // consumed by k_scan (next dispatch)
  for (int k = t; k < NBIN; k += HT) h[k] = 0u;
  __syncthreads();
  int chunk = (n + HB - 1) / HB;
  int i0 = b * chunk, i1 = min(n, i0 + chunk);
  float vs = vs_p[0];
  for (int i = i0 + t; i < i1; i += HT) {
    float x = pos[3 * (size_t)i + 0];
    float y = pos[3 * (size_t)i + 1];
    float z = pos[3 * (size_t)i + 2];
    int lin = (int)floorf(x / vs) + STRIDE * (int)floorf(y / vs) +
              STRIDE * STRIDE * (int)floorf(z / vs);
    lin_arr[i] = lin;
    bytemap[lin] = 1;
    atomicAdd(&h[lin >> 9], 1u);  // LDS atomic
  }
  __syncthreads();
  for (int k = t; k < NBIN; k += HT) hist[(size_t)b * NBIN + k] = h[k];
}

// 2: fused scan (was scanA + scan64). 16 co-resident blocks; device-scope
//    seg-total exchange + spin barrier; emits base2, tot2, bin_base,
//    occ_base, M in ONE dispatch.
__global__ __launch_bounds__(SEGBINS) void k_scan(
    const uint32_t* __restrict__ hist, const uint32_t* __restrict__ bytemap_w,
    uint32_t* __restrict__ base2, u64* __restrict__ tot2,
    uint32_t* __restrict__ bin_base, uint32_t* __restrict__ occ_base,
    uint32_t* __restrict__ sync, u64* __restrict__ seg_tot,
    uint32_t* __restrict__ Mp) {
  __shared__ u64 s[SEGBINS];
  int b = blockIdx.x, t = threadIdx.x;
  int bin = b * SEGBINS + t;
  // per-bin exclusive scan across the 256 chunk histograms
  uint32_t run = 0;
  #pragma unroll 8
  for (int c = 0; c < HB; ++c) {
    base2[(size_t)c * NBIN + bin] = run;
    run += hist[(size_t)c * NBIN + bin];
  }
  // occupied-voxel count from bytemap (bytes == 1 only; exact SWAR)
  const uint4* bp = (const uint4*)bytemap_w + (size_t)bin * 32;  // 512 B
  uint32_t occ = 0;
  #pragma unroll
  for (int k = 0; k < 32; ++k) {
    uint4 v = bp[k];
    occ += cnt_eq1(v.x) + cnt_eq1(v.y) + cnt_eq1(v.z) + cnt_eq1(v.w);
  }
  u64 mine = (u64)run | ((u64)occ << 32);
  tot2[bin] = mine;
  // intra-block exclusive scan over 256 packed u64
  s[t] = mine;
  __syncthreads();
  for (int off = 1; off < SEGBINS; off <<= 1) {
    u64 a = (t >= off) ? s[t - off] : 0ull;
    __syncthreads();
    s[t] += a;
    __syncthreads();
  }
  u64 excl = s[t] - mine;
  u64 blk_total = s[SEGBINS - 1];
  // cross-block: publish segment total, spin for all 16
  if (t == 0) {
    __hip_atomic_store(&seg_tot[b], blk_total, __ATOMIC_RELEASE,
                       __HIP_MEMORY_SCOPE_AGENT);
    __hip_atomic_fetch_add(sync, 1u, __ATOMIC_ACQ_REL, __HIP_MEMORY_SCOPE_AGENT);
    while (__hip_atomic_load(sync, __ATOMIC_ACQUIRE, __HIP_MEMORY_SCOPE_AGENT) <
           (uint32_t)NSEG) {}
  }
  __syncthreads();
  u64 pre = 0, grand = 0;
  #pragma unroll
  for (int i = 0; i < NSEG; ++i) {
    u64 v = __hip_atomic_load(&seg_tot[i], __ATOMIC_ACQUIRE,
                              __HIP_MEMORY_SCOPE_AGENT);
    if (i < b) pre += v;
    grand += v;
  }
  u64 g = pre + excl;
  bin_base[bin] = (uint32_t)g;
  occ_base[bin] = (uint32_t)(g >> 32);
  if (b == 0 && t == 0) Mp[0] = (uint32_t)(grand >> 32);
}

// 3: partition with LDS cursors (no global atomics); same chunk map as k_hist
__global__ __launch_bounds__(HT) void k_part(const int* __restrict__ lin_arr,
                                             const uint32_t* __restrict__ bin_base,
                                             const uint32_t* __restrict__ base2,
                                             uint32_t* __restrict__ pairs, int n) {
  __shared__ uint32_t cur[NBIN];  // 16 KB
  int b = blockIdx.x, t = threadIdx.x;
  for (int k = t; k < NBIN; k += HT)
    cur[k] = bin_base[k] + base2[(size_t)b * NBIN + k];
  __syncthreads();
  int chunk = (n + HB - 1) / HB;
  int i0 = b * chunk, i1 = min(n, i0 + chunk);
  for (int i = i0 + t; i < i1; i += HT) {
    int lin = lin_arr[i];
    uint32_t slot = atomicAdd(&cur[lin >> 9], 1u);  // LDS atomic
    pairs[slot] = ((uint32_t)(lin & (BINVOX - 1)) << 21) | (uint32_t)i;
  }
}

// 4: FUSED pool + tail. Blocks [0,NBIN): per-bin LDS max-pool.
//    Blocks [NBIN, ...): zero pos/valid for rows >= M and feat rows in
//    [M, srow) -- disjoint from pool writes (< M) and from the scratch
//    (>= srow), so both roles run concurrently in one dispatch.
__global__ __launch_bounds__(1024) void k_pool(
    const float* __restrict__ feat, const float* __restrict__ vs_p,
    const uint32_t* __restrict__ pairs, const uint32_t* __restrict__ bin_base,
    const u64* __restrict__ tot2, const uint32_t* __restrict__ occ_base,
    const uint8_t* __restrict__ bytemap, const uint32_t* __restrict__ Mp,
    float* __restrict__ out_pos, float* __restrict__ out_feat,
    float* __restrict__ out_valid, int n, int srow) {
  __shared__ uint32_t smax[BINVOX * 32];  // 64 KB
  __shared__ u64 sbw[8];
  int t = threadIdx.x;

  if (blockIdx.x >= NBIN) {  // ---- tail role ----
    size_t gid = (size_t)(blockIdx.x - NBIN) * 1024 + t;
    int row = (int)(gid >> 3);
    int q = (int)(gid & 7);
    if (row >= n) return;
    uint32_t M = Mp[0];
    if ((uint32_t)row < M) return;
    if (row < srow)
      ((float4*)out_feat)[(size_t)row * 8 + q] = make_float4(0.f, 0.f, 0.f, 0.f);
    if (q == 0) {
      out_pos[(size_t)row * 3 + 0] = 0.f;
      out_pos[(size_t)row * 3 + 1] = 0.f;
      out_pos[(size_t)row * 3 + 2] = 0.f;
      out_valid[row] = 0.f;
    }
    return;
  }

  // ---- pool role ----
  int bin = blockIdx.x;
  uint32_t cnt = (uint32_t)tot2[bin];
  if (cnt == 0) return;  // uniform exit (before any barrier)
  uint32_t start = bin_base[bin];

  #pragma unroll
  for (int k = 0; k < 16; ++k) smax[t + k * 1024] = 0u;
  if (t < 512) {  // waves 0..7 exactly; ballot is wave-uniform
    uint32_t occb = bytemap[(size_t)bin * BINVOX + t];
    u64 m = __ballot(occb == 1u);
    if ((t & 63) == 0) sbw[t >> 6] = m;
  }
  __syncthreads();

  int g = t >> 5;    // point group 0..31
  int ch = t & 31;   // channel
  uint32_t last = cnt - 1;
  for (uint32_t u = (uint32_t)g; u < cnt; u += 256) {
    uint32_t p0 = pairs[start + u];
    uint32_t p1 = pairs[start + min(u + 32u, last)];
    uint32_t p2 = pairs[start + min(u + 64u, last)];
    uint32_t p3 = pairs[start + min(u + 96u, last)];
    uint32_t p4 = pairs[start + min(u + 128u, last)];
    uint32_t p5 = pairs[start + min(u + 160u, last)];
    uint32_t p6 = pairs[start + min(u + 192u, last)];
    uint32_t p7 = pairs[start + min(u + 224u, last)];
    float v0 = feat[(size_t)(p0 & 0x1FFFFFu) * 32 + ch];
    float v1 = feat[(size_t)(p1 & 0x1FFFFFu) * 32 + ch];
    float v2 = feat[(size_t)(p2 & 0x1FFFFFu) * 32 + ch];
    float v3 = feat[(size_t)(p3 & 0x1FFFFFu) * 32 + ch];
    float v4 = feat[(size_t)(p4 & 0x1FFFFFu) * 32 + ch];
    float v5 = feat[(size_t)(p5 & 0x1FFFFFu) * 32 + ch];
    float v6 = feat[(size_t)(p6 & 0x1FFFFFu) * 32 + ch];
    float v7 = feat[(size_t)(p7 & 0x1FFFFFu) * 32 + ch];
    atomicMax(&smax[(p0 >> 21) * 32 + ch], enc_f32(v0));
    atomicMax(&smax[(p1 >> 21) * 32 + ch], enc_f32(v1));
    atomicMax(&smax[(p2 >> 21) * 32 + ch], enc_f32(v2));
    atomicMax(&smax[(p3 >> 21) * 32 + ch], enc_f32(v3));
    atomicMax(&smax[(p4 >> 21) * 32 + ch], enc_f32(v4));
    atomicMax(&smax[(p5 >> 21) * 32 + ch], enc_f32(v5));
    atomicMax(&smax[(p6 >> 21) * 32 + ch], enc_f32(v6));
    atomicMax(&smax[(p7 >> 21) * 32 + ch], enc_f32(v7));
  }
  __syncthreads();

  int vb = t >> 1, half = t & 1;
  u64 w = sbw[vb >> 6];
  int bit = vb & 63;
  if ((w >> bit) & 1ull) {
    uint32_t lr = (uint32_t)__popcll(w & ((1ull << bit) - 1ull));
    for (int ww = 0; ww < (vb >> 6); ++ww) lr += (uint32_t)__popcll(sbw[ww]);
    uint32_t rank = occ_base[bin] + lr;
    float4* orow = (float4*)(out_feat + (size_t)rank * 32 + half * 16);
    #pragma unroll
    for (int j = 0; j < 4; ++j) {
      const uint32_t* sp = &smax[vb * 32 + half * 16 + j * 4];
      float4 o;
      o.x = dec_f32(sp[0]); o.y = dec_f32(sp[1]);
      o.z = dec_f32(sp[2]); o.w = dec_f32(sp[3]);
      orow[j] = o;
    }
    if (half == 0) {
      float vs = vs_p[0];
      int lin = bin * BINVOX + vb;
      int cx = lin & 127, cy = (lin >> 7) & 127, cz = lin >> 14;
      out_pos[(size_t)rank * 3 + 0] = ((float)cx + 0.5f) * vs;
      out_pos[(size_t)rank * 3 + 1] = ((float)cy + 0.5f) * vs;
      out_pos[(size_t)rank * 3 + 2] = ((float)cz + 0.5f) * vs;
      out_valid[rank] = 1.0f;
    }
  }
}

// 5: wipe the scratch region (feat rows >= srow), incl. bytemap -> all zero
__global__ void k_tail2(float4* __restrict__ dst, long long cnt4) {
  long long i = (long long)blockIdx.x * blockDim.x + threadIdx.x;
  if (i < cnt4) dst[i] = make_float4(0.f, 0.f, 0.f, 0.f);
}

extern "C" void kernel_launch(void* const* d_in, const int* in_sizes, int n_in,
                              void* d_out, int out_size, void* d_ws, size_t ws_size,
                              hipStream_t stream) {
  const float* pos  = (const float*)d_in[0];
  const float* feat = (const float*)d_in[1];
  const float* vs   = (const float*)d_in[2];
  int n = in_sizes[0] / 3;  // 2,000,000

  float*    out_pos   = (float*)d_out;
  uint32_t* out_feat  = (uint32_t*)(out_pos + (size_t)n * 3);
  float*    out_valid = (float*)((float*)out_feat + (size_t)n * 32);

  // Scratch in the TAIL of the feature output region (~26.6 MB):
  // lin(n) | pairs(n) | hist[HB][NBIN] | base2[HB][NBIN] | tot2(u64 NBIN) |
  // bin_base | occ_base | bytemap(NVOX bytes).
  // Rows >= srow (~1,792,568); at most 100^3 = 1e6 distinct voxels -> M <= 1e6,
  // so pool blocks (rows < M) never touch it; fused-tail blocks stop below
  // srow; k_tail2 zeroes [srow, n) afterwards (incl. bytemap -> 0 for next call).
  size_t scratch_u32 = 2 * (size_t)n + 2 * (size_t)HB * NBIN +
                       2 * (size_t)NBIN + 2 * (size_t)NBIN + NVOX / 4;
  uint32_t* scratch  = out_feat + (size_t)n * 32 - scratch_u32;
  int*      lin      = (int*)scratch;
  uint32_t* pairs    = scratch + n;
  uint32_t* hist     = pairs + n;                          // HB*NBIN
  uint32_t* base2    = hist + (size_t)HB * NBIN;           // HB*NBIN
  u64*      tot2     = (u64*)(base2 + (size_t)HB * NBIN);  // NBIN u64
  uint32_t* bin_base = (uint32_t*)(tot2 + NBIN);           // NBIN
  uint32_t* occ_base = bin_base + NBIN;                    // NBIN
  uint8_t*  bytemap  = (uint8_t*)(occ_base + NBIN);        // NVOX bytes

  int srow = (int)(((size_t)n * 32 - scratch_u32) / 32);   // first scratch row

  uint32_t* Mp   = (uint32_t*)d_ws;
  uint32_t* sync = Mp + 1;
  u64*      seg_tot = (u64*)(Mp + 2);  // 8-byte aligned (offset 8)

  k_hist<<<HB, HT, 0, stream>>>(pos, vs, lin, bytemap, hist, sync, n);
  k_scan<<<NSEG, SEGBINS, 0, stream>>>(hist, (const uint32_t*)bytemap, base2,
                                       tot2, bin_base, occ_base, sync, seg_tot, Mp);
  k_part<<<HB, HT, 0, stream>>>(lin, bin_base, base2, pairs, n);
  int tail_blocks = (int)(((size_t)n * 8 + 1023) / 1024);
  k_pool<<<NBIN + tail_blocks, 1024, 0, stream>>>(
      feat, vs, pairs, bin_base, tot2, occ_base, bytemap, Mp,
      out_pos, (float*)out_feat, out_valid, n, srow);
  long long cnt4 = ((long long)n * 32 - (long long)srow * 32) / 4;
  k_tail2<<<(int)((cnt4 + 1023) / 1024), 1024, 0, stream>>>(
      (float4*)(out_feat + (size_t)srow * 32), cnt4);
}